// Round 6
// baseline (439.649 us; speedup 1.0000x reference)
//
#include <hip/hip_runtime.h>

typedef unsigned long long u64;
typedef unsigned short ushort_t;
typedef unsigned int uint32;

#define NNODES 12288
#define WORDS 192    // 12288 / 64 bits per row
#define ELLW 256     // max neighbors per row (avg ~64)
#define ZROW NNODES  // zeroed pad row index
#define LDB 520      // LDS A-frag c-block stride in shorts (bank-rotates 4 words/block)
#define RMS 264      // row-major bounce stride in shorts ([16][264])
#define HCW1B 491520 // frag base of hc_w1 (64x128) in W buffer
#define HCW2B 507904 // frag base of hc_w2 (8x64, cols 8-15 zeroed)
#define PBF 8        // partial-sum LDS stride in floats

typedef __attribute__((ext_vector_type(8))) short short8_t;   // 8 bf16 (4 VGPRs)
typedef __attribute__((ext_vector_type(4))) float f32x4;      // MFMA C/D frag
typedef __attribute__((ext_vector_type(2))) float f32x2;      // packed-add pair

// ---- bf16 split helpers (RNE) ----
__device__ __forceinline__ ushort_t f2bf(float f) {
    uint32 u = __float_as_uint(f);
    return (ushort_t)((u + 0x7fffu + ((u >> 16) & 1u)) >> 16);
}
__device__ __forceinline__ float bf2f(ushort_t h) {
    return __uint_as_float(((uint32)h) << 16);
}

// ---------------- K1: build_mask || W swizzle (incl hc) || pad/gf clear ------
__global__ __launch_bounds__(512) void prep_kernel(
        const int* __restrict__ ei, int E, int nbB,
        u64* __restrict__ M, u64* __restrict__ MT,
        const float* __restrict__ e1, const float* __restrict__ e2,
        const float* __restrict__ gi, const float* __restrict__ gl,
        const float* __restrict__ go, const float* __restrict__ pj,
        const float* __restrict__ hw1, const float* __restrict__ hw2,
        ushort_t* __restrict__ hi, ushort_t* __restrict__ lo,
        ushort_t* __restrict__ xah, ushort_t* __restrict__ xal,
        ushort_t* __restrict__ xbh, ushort_t* __restrict__ xbl,
        float* __restrict__ gf) {
    int b = blockIdx.x;
    int t = threadIdx.x;
    if (b < nbB) {
        int e = b * 512 + t;
        if (e >= E) return;
        int s = ei[e];
        int d = ei[E + e];
        atomicOr(&M[(size_t)s * WORDS + (d >> 6)], 1ull << (d & 63));
        atomicOr(&MT[(size_t)d * WORDS + (s >> 6)], 1ull << (s & 63));
        return;
    }
    int wb = b - nbB;
    if (wb < 960) {                       // main W: 491520 elems exactly
        int i = wb * 512 + t;
        float v;
        if (i < 131072)      v = (i < 65536) ? e1[i] : e2[i - 65536];
        else if (i < 196608) v = gi[i - 131072];
        else if (i < 393216) v = gl[i - 196608];
        else if (i < 458752) v = go[i - 393216];
        else                 v = pj[i - 458752];
        int base = (i < 458752) ? (i & ~65535) : 458752;
        int r = i - base;
        int col = r >> 8, k = r & 255;
        int ct = col >> 4, fr = col & 15;
        int c = k >> 5, fq = (k >> 3) & 3, j = k & 7;
        int o = base + (ct * 8 + c) * 512 + (fq * 16 + fr) * 8 + j;
        ushort_t h = f2bf(v);
        hi[o] = h;
        lo[o] = f2bf(v - bf2f(h));
        return;
    }
    if (wb < 976) {                       // hc_w1: 64 cols x 128 k
        int i2 = (wb - 960) * 512 + t;    // [0, 8192)
        int col = i2 >> 7, k = i2 & 127;
        float v = hw1[(size_t)col * 128 + k];
        int o = HCW1B + ((col >> 4) * 8 + (k >> 5)) * 512
              + (((k >> 3) & 3) * 16 + (col & 15)) * 8 + (k & 7);
        ushort_t h = f2bf(v);
        hi[o] = h;
        lo[o] = f2bf(v - bf2f(h));
        return;
    }
    if (wb == 976) {                      // hc_w2: 8 cols x 64 k (+ zero cols 8-15)
        int col = t >> 6, k = t & 63;
        float v = hw2[(size_t)col * 64 + k];
        int o = HCW2B + (k >> 5) * 512 + (((k >> 3) & 3) * 16 + col) * 8 + (k & 7);
        ushort_t h = f2bf(v);
        hi[o] = h;
        lo[o] = f2bf(v - bf2f(h));
        int oz = HCW2B + (k >> 5) * 512 + (((k >> 3) & 3) * 16 + 8 + col) * 8 + (k & 7);
        hi[oz] = 0;
        lo[oz] = 0;
        return;
    }
    // pad rows of X ping-pong pairs + gf zero
    #pragma unroll
    for (int k = 0; k < 4; ++k) {
        size_t off = (size_t)NNODES * 256 + (size_t)k * 512 + t;
        xah[off] = 0; xal[off] = 0; xbh[off] = 0; xbl[off] = 0;
    }
    if (t < 128) gf[t] = 0.0f;
}

// ---------------- gather accumulate helpers ----------------
__device__ __forceinline__ void acc_u4(uint4 u, f32x2* a2) {
    const uint32 HM = 0xFFFF0000u;
    f32x2 t0 = {__uint_as_float(u.x << 16), __uint_as_float(u.x & HM)};
    f32x2 t1 = {__uint_as_float(u.y << 16), __uint_as_float(u.y & HM)};
    f32x2 t2 = {__uint_as_float(u.z << 16), __uint_as_float(u.z & HM)};
    f32x2 t3 = {__uint_as_float(u.w << 16), __uint_as_float(u.w & HM)};
    a2[0] += t0; a2[1] += t1; a2[2] += t2; a2[3] += t3;
}

// combine self (hi+lo) + dv*acc over 8 cols, split back into bf16 hi/lo octets
__device__ __forceinline__ void pack_pair(uint4 uh, uint4 ul, const float* a, float dv,
                                          short8_t& oh, short8_t& ol) {
    const uint32 HM = 0xFFFF0000u;
    uint32 hu[4] = {uh.x, uh.y, uh.z, uh.w};
    uint32 lu[4] = {ul.x, ul.y, ul.z, ul.w};
    #pragma unroll
    for (int q = 0; q < 4; ++q) {
        float xlo = __uint_as_float(hu[q] << 16) + __uint_as_float(lu[q] << 16);
        float xhi = __uint_as_float(hu[q] & HM) + __uint_as_float(lu[q] & HM);
        float s0 = xlo + dv * a[2 * q];
        float s1 = xhi + dv * a[2 * q + 1];
        ushort_t p0 = f2bf(s0), p1 = f2bf(s1);
        oh[2 * q]     = (short)p0;
        oh[2 * q + 1] = (short)p1;
        ol[2 * q]     = (short)f2bf(s0 - bf2f(p0));
        ol[2 * q + 1] = (short)f2bf(s1 - bf2f(p1));
    }
}

// ---------------- 16-row band-GEMM (frag-swizzled A in LDS, B from L2) -------
// A-frag LDS: c-blocks of LDB shorts, addr = c*LDB + (fq*16 + r)*8 + j
template<int NTW, int NC>
__device__ __forceinline__ void band_step16(
        const ushort_t* Ah, const ushort_t* Al,
        const ushort_t* __restrict__ Wh, const ushort_t* __restrict__ Wl,
        int w, int lane, f32x4 (&acc)[NTW]) {
    int ct0 = w * NTW;
    short8_t bh[NTW], bl[NTW];
    #pragma unroll
    for (int nt = 0; nt < NTW; ++nt) {
        size_t bo = (size_t)((ct0 + nt) * 8) * 512 + lane * 8;
        bh[nt] = *(const short8_t*)&Wh[bo];
        bl[nt] = *(const short8_t*)&Wl[bo];
    }
    #pragma unroll
    for (int c = 0; c < NC; ++c) {
        short8_t bhn[NTW], bln[NTW];
        if (c < NC - 1) {
            #pragma unroll
            for (int nt = 0; nt < NTW; ++nt) {
                size_t bo = (size_t)((ct0 + nt) * 8 + c + 1) * 512 + lane * 8;
                bhn[nt] = *(const short8_t*)&Wh[bo];
                bln[nt] = *(const short8_t*)&Wl[bo];
            }
        }
        short8_t ah = *(const short8_t*)&Ah[c * LDB + lane * 8];
        short8_t al = *(const short8_t*)&Al[c * LDB + lane * 8];
        #pragma unroll
        for (int nt = 0; nt < NTW; ++nt) {
            f32x4 a = acc[nt];
            a = __builtin_amdgcn_mfma_f32_16x16x32_bf16(ah, bh[nt], a, 0, 0, 0);
            a = __builtin_amdgcn_mfma_f32_16x16x32_bf16(ah, bl[nt], a, 0, 0, 0);
            a = __builtin_amdgcn_mfma_f32_16x16x32_bf16(al, bh[nt], a, 0, 0, 0);
            acc[nt] = a;
        }
        if (c < NC - 1) {
            #pragma unroll
            for (int nt = 0; nt < NTW; ++nt) { bh[nt] = bhn[nt]; bl[nt] = bln[nt]; }
        }
    }
}

template<int NTW>
__device__ __forceinline__ void acc_zero16(f32x4 (&acc)[NTW]) {
    #pragma unroll
    for (int b = 0; b < NTW; ++b) {
        f32x4 z = {0.f, 0.f, 0.f, 0.f};
        acc[b] = z;
    }
}

// bias + optional relu, split to hi/lo, store in FRAG layout (multi-tile form)
template<int NTW, bool RELU>
__device__ __forceinline__ void acc_to_lds16(
        f32x4 (&acc)[NTW], const float* __restrict__ bias,
        int w, int lane, ushort_t* Ah, ushort_t* Al) {
    int fr = lane & 15, fq = lane >> 4;
    int col0 = w * (16 * NTW);
    #pragma unroll
    for (int nt = 0; nt < NTW; ++nt) {
        int col = col0 + 16 * nt + fr;         // next-step k index
        float bb = bias[col];
        int c = col >> 5, fqn = (col >> 3) & 3, jn = col & 7;
        #pragma unroll
        for (int e = 0; e < 4; ++e) {
            int r = fq * 4 + e;                // 0..15
            float v = acc[nt][e] + bb;
            if (RELU) v = fmaxf(v, 0.0f);
            ushort_t h = f2bf(v);
            int addr = c * LDB + (fqn * 16 + r) * 8 + jn;
            Ah[addr] = h;
            Al[addr] = f2bf(v - bf2f(h));
        }
    }
}

// single-tile frag write for 16-wave GEMMs (col = w*16 + fr)
template<bool RELU>
__device__ __forceinline__ void acc_to_lds1(
        f32x4& acc, const float* __restrict__ bias,
        int w, int lane, ushort_t* Ah, ushort_t* Al) {
    int fr = lane & 15, fq = lane >> 4;
    int col = w * 16 + fr;
    float bb = bias[col];
    int c = col >> 5, fqn = (col >> 3) & 3, jn = col & 7;
    #pragma unroll
    for (int e = 0; e < 4; ++e) {
        int r = fq * 4 + e;
        float v = acc[e] + bb;
        if (RELU) v = fmaxf(v, 0.0f);
        ushort_t h = f2bf(v);
        int addr = c * LDB + (fqn * 16 + r) * 8 + jn;
        Ah[addr] = h;
        Al[addr] = f2bf(v - bf2f(h));
    }
}

// single-tile bounce write (row-major [16][RMS]), relu fixed (gl layers)
__device__ __forceinline__ void acc_to_rows1(
        f32x4& acc, const float* __restrict__ bias,
        int w, int lane, ushort_t* Rh, ushort_t* Rl) {
    int fr = lane & 15, fq = lane >> 4;
    int gc = w * 16 + fr;
    float bb = bias[gc];
    #pragma unroll
    for (int e = 0; e < 4; ++e) {
        int r = fq * 4 + e;
        float v = fmaxf(acc[e] + bb, 0.0f);
        ushort_t h = f2bf(v);
        Rh[r * RMS + gc] = h;
        Rl[r * RMS + gc] = f2bf(v - bf2f(h));
    }
}

// coalesced flush of row-major bounce buffers to global [N][256] pair
__device__ __forceinline__ void rows_to_global(
        const ushort_t* Rh, const ushort_t* Rl, int row0, int tid,
        ushort_t* __restrict__ Yh, ushort_t* __restrict__ Yl) {
    int r = tid >> 5, kq = tid & 31;
    short8_t vh = *(const short8_t*)&Rh[r * RMS + kq * 8];
    short8_t vl = *(const short8_t*)&Rl[r * RMS + kq * 8];
    size_t off = (size_t)(row0 + r) * 256 + kq * 8;
    *(short8_t*)&Yh[off] = vh;
    *(short8_t*)&Yl[off] = vl;
}

// ---------------- split gather: two 512-thread teams per 16-row band ---------
// team h sums neighbor 8-groups {h, h+2, ...}; team 1 parks partials in PB;
// team 0 combines (a = a_h0 + a_h1 elementwise), packs, writes frag LDS.
// Rows with n<=8: team-1 partial is exactly zero -> bit-identical result.
__device__ __forceinline__ void gather_band_split(
        const ushort_t* __restrict__ Xh_, const ushort_t* __restrict__ Xl_,
        const ushort_t* __restrict__ ell, const int* __restrict__ cnt,
        const float* __restrict__ dinv, int row0, int tid,
        ushort_t* Ah, ushort_t* Al, float* PB) {
    int h = tid >> 9, t2 = tid & 511;
    int r = t2 >> 5, cg = t2 & 31;
    int row = row0 + r;
    int n = cnt[row];
    int np8 = (n + 7) & ~7;
    const ushort_t* rell = ell + (size_t)row * ELLW;
    const ushort_t* xb = Xh_ + cg * 8;
    f32x2 a2[4] = {};
    ushort4 ja = *(const ushort4*)&rell[h * 8];
    ushort4 jb = *(const ushort4*)&rell[h * 8 + 4];
    for (int i = h * 8; i < np8; i += 16) {
        ushort4 jan = *(const ushort4*)&rell[i + 16];
        ushort4 jbn = *(const ushort4*)&rell[i + 20];
        uint4 u0 = *(const uint4*)&xb[(size_t)ja.x * 256];
        uint4 u1 = *(const uint4*)&xb[(size_t)ja.y * 256];
        uint4 u2 = *(const uint4*)&xb[(size_t)ja.z * 256];
        uint4 u3 = *(const uint4*)&xb[(size_t)ja.w * 256];
        uint4 u4 = *(const uint4*)&xb[(size_t)jb.x * 256];
        uint4 u5 = *(const uint4*)&xb[(size_t)jb.y * 256];
        uint4 u6 = *(const uint4*)&xb[(size_t)jb.z * 256];
        uint4 u7 = *(const uint4*)&xb[(size_t)jb.w * 256];
        acc_u4(u0, a2); acc_u4(u1, a2); acc_u4(u2, a2); acc_u4(u3, a2);
        acc_u4(u4, a2); acc_u4(u5, a2); acc_u4(u6, a2); acc_u4(u7, a2);
        ja = jan; jb = jbn;
    }
    if (h) {
        *(float4*)&PB[t2 * PBF] =
            make_float4(a2[0][0], a2[0][1], a2[1][0], a2[1][1]);
        *(float4*)&PB[t2 * PBF + 4] =
            make_float4(a2[2][0], a2[2][1], a2[3][0], a2[3][1]);
    }
    __syncthreads();
    if (!h) {
        float4 p0 = *(const float4*)&PB[t2 * PBF];
        float4 p1 = *(const float4*)&PB[t2 * PBF + 4];
        a2[0][0] += p0.x; a2[0][1] += p0.y;
        a2[1][0] += p0.z; a2[1][1] += p0.w;
        a2[2][0] += p1.x; a2[2][1] += p1.y;
        a2[3][0] += p1.z; a2[3][1] += p1.w;
        const float* a = (const float*)a2;
        float dv = dinv[row];
        size_t so = (size_t)row * 256 + cg * 8;
        uint4 h0 = *(const uint4*)&Xh_[so];
        uint4 l0 = *(const uint4*)&Xl_[so];
        short8_t gh, gl;
        pack_pair(h0, l0, a, dv, gh, gl);
        int addr = (cg >> 2) * LDB + ((cg & 3) * 16 + r) * 8;
        *(short8_t*)&Ah[addr] = gh;
        *(short8_t*)&Al[addr] = gl;
    }
}

// ---------------- K2: fused encoder || ell_fill ----------------
__global__ __launch_bounds__(512) void enc_ell_kernel(
        const float* __restrict__ nf,
        const ushort_t* __restrict__ Wh, const ushort_t* __restrict__ Wl,
        const float* __restrict__ b1, const float* __restrict__ b2,
        const float* __restrict__ b3,
        ushort_t* __restrict__ xh, ushort_t* __restrict__ xl,
        const u64* __restrict__ M, const u64* __restrict__ MT,
        ushort_t* __restrict__ ell, int* __restrict__ cnt, float* __restrict__ dinv) {
    __shared__ __align__(16) ushort_t Ah[16 * RMS];
    __shared__ __align__(16) ushort_t Al[16 * RMS];
    int tid = threadIdx.x;
    int lane = tid & 63;
    if (blockIdx.x >= 768) {
        // ---- ell_fill branch: one wave per row ----
        int row = (blockIdx.x - 768) * 8 + (tid >> 6);
        const u64* rM  = M  + (size_t)row * WORDS;
        const u64* rMT = MT + (size_t)row * WORDS;
        u64 wm[3], wt[3];
        int pm = 0, pt = 0;
        #pragma unroll
        for (int k = 0; k < 3; ++k) {
            wm[k] = rM[lane + 64 * k];  pm += __popcll(wm[k]);
            wt[k] = rMT[lane + 64 * k]; pt += __popcll(wt[k]);
        }
        int inclM = pm, inclT = pt;
        #pragma unroll
        for (int off = 1; off < 64; off <<= 1) {
            int ym = __shfl_up(inclM, off, 64);
            int yt = __shfl_up(inclT, off, 64);
            if (lane >= off) { inclM += ym; inclT += yt; }
        }
        int exclM = inclM - pm;
        int exclT = inclT - pt;
        int totM = __shfl(inclM, 63, 64);
        int totT = __shfl(inclT, 63, 64);
        ushort_t* out = ell + (size_t)row * ELLW;
        int pos = exclM;
        #pragma unroll
        for (int k = 0; k < 3; ++k) {
            u64 bits = wm[k];
            int base = (lane + 64 * k) << 6;
            while (bits) { out[pos++] = (ushort_t)(base + __builtin_ctzll(bits)); bits &= bits - 1; }
        }
        pos = totM + exclT;
        #pragma unroll
        for (int k = 0; k < 3; ++k) {
            u64 bits = wt[k];
            int base = (lane + 64 * k) << 6;
            while (bits) { out[pos++] = (ushort_t)(base + __builtin_ctzll(bits)); bits &= bits - 1; }
        }
        if (lane == 0) {
            int n = totM + totT;
            int np = (n + 7) & ~7;
            for (int p = n; p < np; ++p) out[p] = (ushort_t)ZROW;
            cnt[row] = n;
            dinv[row] = 1.0f / ((float)n + 1e-8f);
        }
        return;
    }
    // ---- encoder branch ----
    int w = __builtin_amdgcn_readfirstlane(tid >> 6);   // 0..7
    int row0 = blockIdx.x * 16;

    // stage nf band (16 rows x 64 float4) with on-the-fly hi/lo split
    #pragma unroll
    for (int i = 0; i < 2; ++i) {
        int s = i * 512 + tid;             // 1024 float4 slots
        int r = s >> 6, k4 = s & 63;
        float4 v = *(const float4*)&nf[(size_t)(row0 + r) * 256 + k4 * 4];
        ushort_t h0 = f2bf(v.x), h1 = f2bf(v.y), h2 = f2bf(v.z), h3 = f2bf(v.w);
        int kq = k4 >> 1, half = (k4 & 1) * 4;
        int c = kq >> 2, fqs = kq & 3;
        int addr = c * LDB + (fqs * 16 + r) * 8 + half;
        *(ushort4*)&Ah[addr] = make_ushort4(h0, h1, h2, h3);
        *(ushort4*)&Al[addr] =
            make_ushort4(f2bf(v.x - bf2f(h0)), f2bf(v.y - bf2f(h1)),
                         f2bf(v.z - bf2f(h2)), f2bf(v.w - bf2f(h3)));
    }
    __syncthreads();

    f32x4 acc[2];
    // enc1 (relu)
    acc_zero16<2>(acc);
    band_step16<2, 8>(Ah, Al, Wh, Wl, w, lane, acc);
    __syncthreads();
    acc_to_lds16<2, true>(acc, b1, w, lane, Ah, Al);
    __syncthreads();
    // enc2 (no relu)
    acc_zero16<2>(acc);
    band_step16<2, 8>(Ah, Al, Wh + 65536, Wl + 65536, w, lane, acc);
    __syncthreads();
    acc_to_lds16<2, false>(acc, b2, w, lane, Ah, Al);
    __syncthreads();
    // gin (relu) -> row-major bounce -> coalesced X0 pair stores
    acc_zero16<2>(acc);
    band_step16<2, 8>(Ah, Al, Wh + 131072, Wl + 131072, w, lane, acc);
    __syncthreads();
    {
        int fr = lane & 15, fq = lane >> 4;
        int col0 = w * 32;
        #pragma unroll
        for (int nt = 0; nt < 2; ++nt) {
            int gc = col0 + 16 * nt + fr;
            float bb = b3[gc];
            #pragma unroll
            for (int e = 0; e < 4; ++e) {
                int r = fq * 4 + e;
                float v = fmaxf(acc[nt][e] + bb, 0.0f);
                ushort_t h = f2bf(v);
                Ah[r * RMS + gc] = h;
                Al[r * RMS + gc] = f2bf(v - bf2f(h));
            }
        }
    }
    __syncthreads();
    rows_to_global(Ah, Al, row0, tid, xh, xl);
}

// ---------------- fused GNN layer (layers 1,2): gather -> GEMM -> Y ----------
// 1024 threads, 2 blocks/CU = 32 waves/CU (the grid was the occupancy cap).
__global__ __launch_bounds__(1024, 8) void fused_layer_kernel(
        const ushort_t* __restrict__ Xh_, const ushort_t* __restrict__ Xl_,
        const ushort_t* __restrict__ ell, const int* __restrict__ cnt,
        const float* __restrict__ dinv,
        const ushort_t* __restrict__ Wh, const ushort_t* __restrict__ Wl,
        const float* __restrict__ bias,
        ushort_t* __restrict__ Yh, ushort_t* __restrict__ Yl) {
    __shared__ __align__(16) ushort_t Ah[16 * RMS];
    __shared__ __align__(16) ushort_t Al[16 * RMS];
    __shared__ __align__(16) float PB[512 * PBF];
    int tid = threadIdx.x;
    int lane = tid & 63;
    int w = __builtin_amdgcn_readfirstlane(tid >> 6);   // 0..15
    int row0 = blockIdx.x * 16;
    gather_band_split(Xh_, Xl_, ell, cnt, dinv, row0, tid, Ah, Al, PB);
    __syncthreads();
    f32x4 acc[1];
    acc_zero16<1>(acc);
    band_step16<1, 8>(Ah, Al, Wh, Wl, w, lane, acc);
    __syncthreads();                       // frag reads done -> reuse as bounce
    acc_to_rows1(acc[0], bias, w, lane, Ah, Al);
    __syncthreads();
    if (tid < 512) rows_to_global(Ah, Al, row0, tid, Yh, Yl);
}

// ------- fused last layer + output: gather -> gl3 -> gout -> proj -> hc -------
__global__ __launch_bounds__(1024, 8) void fused_layer_out_kernel(
        const ushort_t* __restrict__ Xh_, const ushort_t* __restrict__ Xl_,
        const ushort_t* __restrict__ ell, const int* __restrict__ cnt,
        const float* __restrict__ dinv,
        const ushort_t* __restrict__ Wh, const ushort_t* __restrict__ Wl,
        const float* __restrict__ gl_b2,
        const float* __restrict__ gout_b, const float* __restrict__ proj_b,
        const float* __restrict__ hc_b1, const float* __restrict__ hc_b2,
        float* __restrict__ ne, float* __restrict__ logits, float* __restrict__ gf) {
    __shared__ __align__(16) ushort_t Ah[16 * RMS];   // frag uses first 8*LDB
    __shared__ __align__(16) ushort_t Al[16 * RMS];
    __shared__ __align__(16) float PB[512 * PBF];
    __shared__ __align__(16) float Pf[16 * 132];      // exact f32 proj (ne + mean)
    int tid = threadIdx.x;
    int lane = tid & 63;
    int w = __builtin_amdgcn_readfirstlane(tid >> 6);   // 0..15
    int row0 = blockIdx.x * 16;
    int fr = lane & 15, fq = lane >> 4;

    // layer-3 gather (into frag LDS) + GEMM; result stays on-chip
    gather_band_split(Xh_, Xl_, ell, cnt, dinv, row0, tid, Ah, Al, PB);
    __syncthreads();
    f32x4 acc[1];
    acc_zero16<1>(acc);
    band_step16<1, 8>(Ah, Al, Wh + 327680, Wl + 327680, w, lane, acc);
    __syncthreads();
    acc_to_lds1<true>(acc[0], gl_b2, w, lane, Ah, Al);
    __syncthreads();

    // gout (no relu) -> frag LDS pair
    acc_zero16<1>(acc);
    band_step16<1, 8>(Ah, Al, Wh + 393216, Wl + 393216, w, lane, acc);
    __syncthreads();
    acc_to_lds1<false>(acc[0], gout_b, w, lane, Ah, Al);
    __syncthreads();

    // proj (relu), 128 cols: waves 0-7 x 16 cols
    f32x4 acc2[1];
    acc_zero16<1>(acc2);
    if (w < 8)
        band_step16<1, 8>(Ah, Al, Wh + 458752, Wl + 458752, w, lane, acc2);
    __syncthreads();   // all frag reads done

    // proj out -> Pf (exact f32) + frag c0-3 (bf16 pair, hc1 A-operand)
    if (w < 8) {
        int gc = w * 16 + fr;
        float bb = proj_b[gc];
        int c = gc >> 5, fqn = (gc >> 3) & 3, jn = gc & 7;
        #pragma unroll
        for (int e = 0; e < 4; ++e) {
            int r = fq * 4 + e;
            float v = fmaxf(acc2[0][e] + bb, 0.0f);
            Pf[r * 132 + gc] = v;
            ushort_t h = f2bf(v);
            int addr = c * LDB + (fqn * 16 + r) * 8 + jn;
            Ah[addr] = h;
            Al[addr] = f2bf(v - bf2f(h));
        }
    }
    __syncthreads();

    // phase: ne bounce (tid<512) || gf mean (tids 128-255) || hc1 MFMA (waves 0-3)
    if (tid < 512) {
        int r = tid >> 5, k4 = tid & 31;
        float4 x = *(const float4*)&Pf[r * 132 + k4 * 4];
        *(float4*)&ne[(size_t)(row0 + r) * 128 + k4 * 4] = x;
    }
    if (tid >= 128 && tid < 256) {
        int col = tid - 128;
        float s = 0.0f;
        #pragma unroll 4
        for (int r = 0; r < 16; ++r) s += Pf[r * 132 + col];
        atomicAdd(&gf[col], s * (1.0f / (float)NNODES));
    }
    if (w < 4) {
        // hc1 (relu): K=128 (c0-3), 64 cols = 4 waves x 16; out -> frag c4,5
        f32x4 acc3[1];
        acc_zero16<1>(acc3);
        band_step16<1, 4>(Ah, Al, Wh + HCW1B, Wl + HCW1B, w, lane, acc3);
        int col64 = w * 16 + fr;
        float bb = hc_b1[col64];
        int c = 4 + (col64 >> 5), fqn = (col64 >> 3) & 3, jn = col64 & 7;
        #pragma unroll
        for (int e = 0; e < 4; ++e) {
            int r = fq * 4 + e;
            float v = fmaxf(acc3[0][e] + bb, 0.0f);
            ushort_t h = f2bf(v);
            int addr = c * LDB + (fqn * 16 + r) * 8 + jn;
            Ah[addr] = h;
            Al[addr] = f2bf(v - bf2f(h));
        }
    }
    __syncthreads();

    // hc2: K=64 from frag c4,5; one wave; cols 0-7 valid (8-15 zero-padded W)
    if (w == 0) {
        f32x4 acc4[1];
        acc_zero16<1>(acc4);
        band_step16<1, 2>(Ah + 4 * LDB, Al + 4 * LDB,
                          Wh + HCW2B, Wl + HCW2B, 0, lane, acc4);
        if (fr < 8) {
            float bb = hc_b2[fr];
            #pragma unroll
            for (int e = 0; e < 4; ++e) {
                int r = fq * 4 + e;
                logits[(size_t)(row0 + r) * 8 + fr] = acc4[0][e] + bb;
            }
        }
    }
}

extern "C" void kernel_launch(void* const* d_in, const int* in_sizes, int n_in,
                              void* d_out, int out_size, void* d_ws, size_t ws_size,
                              hipStream_t stream) {
    const int N = NNODES;
    const float* nf     = (const float*)d_in[0];
    const int*   ei     = (const int*)d_in[1];
    const float* enc_w1 = (const float*)d_in[2];
    const float* enc_b1 = (const float*)d_in[3];
    const float* enc_w2 = (const float*)d_in[4];
    const float* enc_b2 = (const float*)d_in[5];
    const float* gin_w  = (const float*)d_in[6];
    const float* gin_b  = (const float*)d_in[7];
    const float* gl_w   = (const float*)d_in[8];
    const float* gl_b   = (const float*)d_in[9];
    const float* gout_w = (const float*)d_in[10];
    const float* gout_b = (const float*)d_in[11];
    const float* proj_w = (const float*)d_in[12];
    const float* proj_b = (const float*)d_in[13];
    const float* hc_w1  = (const float*)d_in[14];
    const float* hc_b1  = (const float*)d_in[15];
    const float* hc_w2  = (const float*)d_in[16];
    const float* hc_b2  = (const float*)d_in[17];
    const int E = in_sizes[1] >> 1;

    // workspace carve (bytes) -- no aliasing (ws is 256 MiB):
    char* ws = (char*)d_ws;
    u64* M  = (u64*)ws;                                         // 18,874,368
    u64* MT = (u64*)(ws + 18874368);                            // 18,874,368
    ushort_t* XAh = (ushort_t*)(ws + 37748736);                 //  6,295,552
    ushort_t* XAl = (ushort_t*)(ws + 44044288);                 //  6,295,552
    ushort_t* XBh = (ushort_t*)(ws + 50339840);                 //  6,295,552
    ushort_t* XBl = (ushort_t*)(ws + 56635392);                 //  6,295,552
    ushort_t* ell = (ushort_t*)(ws + 62930944);                 //  6,291,456
    int*      cntb = (int*)(ws + 69222400);                     //     49,152
    float*    dinv = (float*)(ws + 69271552);                   //     49,152
    ushort_t* Whi  = (ushort_t*)(ws + 69320704);                //  1,024,000
    ushort_t* Wlo  = (ushort_t*)(ws + 70344704);                //  1,024,000

    float* ne     = (float*)d_out;                        // [N,128]
    float* logits = ne + (size_t)N * 128;                 // [N,8]
    float* gf     = logits + (size_t)N * 8;               // [128]

    hipMemsetAsync(M, 0, 2 * (size_t)N * WORDS * sizeof(u64), stream);

    // K1: build_mask || W swizzle (incl hc_w1/hc_w2) || pad+gf clear
    const int nbB = (E + 511) / 512;       // 768 for E=393216
    prep_kernel<<<nbB + 978, 512, 0, stream>>>(
        ei, E, nbB, M, MT,
        enc_w1, enc_w2, gin_w, gl_w, gout_w, proj_w, hc_w1, hc_w2,
        Whi, Wlo, XAh, XAl, XBh, XBl, gf);

    // K2: fused encoder (768 blocks) || ell_fill (1536 blocks, 8 rows each)
    enc_ell_kernel<<<768 + N / 8, 512, 0, stream>>>(
        nf, Whi, Wlo, enc_b1, enc_b2, gin_b, XAh, XAl,
        M, MT, ell, cntb, dinv);

    const int GB = N / 16;   // 768 band blocks (1024 threads, 2 blocks/CU)
    // layers 1,2 ping-pong XA<->XB; layer 3 fused with the output chain
    fused_layer_kernel<<<GB, 1024, 0, stream>>>(XAh, XAl, ell, cntb, dinv,
                                                Whi + 196608, Wlo + 196608,
                                                gl_b, XBh, XBl);
    fused_layer_kernel<<<GB, 1024, 0, stream>>>(XBh, XBl, ell, cntb, dinv,
                                                Whi + 262144, Wlo + 262144,
                                                gl_b + 256, XAh, XAl);
    fused_layer_out_kernel<<<GB, 1024, 0, stream>>>(
        XAh, XAl, ell, cntb, dinv, Whi, Wlo, gl_b + 512,
        gout_b, proj_b, hc_b1, hc_b2,
        ne, logits, gf);
}

// Round 7
// 300.561 us; speedup vs baseline: 1.4628x; 1.4628x over previous
//
#include <hip/hip_runtime.h>

typedef unsigned long long u64;
typedef unsigned short ushort_t;
typedef unsigned int uint32;

#define NNODES 12288
#define WORDS 192    // 12288 / 64 bits per row
#define ELLW 256     // max neighbors per row (avg ~64)
#define ZROW NNODES  // zeroed pad row index
#define LDB 520      // LDS A-frag c-block stride in shorts (bank-rotates 4 words/block)
#define RMS 264      // row-major bounce stride in shorts ([16][264])
#define HCW1B 491520 // frag base of hc_w1 (64x128) in W buffer
#define HCW2B 507904 // frag base of hc_w2 (8x64, cols 8-15 zeroed)
#define PBF 8        // partial-sum LDS stride in floats (256 threads park 8 floats)

typedef __attribute__((ext_vector_type(8))) short short8_t;   // 8 bf16 (4 VGPRs)
typedef __attribute__((ext_vector_type(4))) float f32x4;      // MFMA C/D frag
typedef __attribute__((ext_vector_type(2))) float f32x2;      // packed-add pair

// ---- bf16 split helpers (RNE) ----
__device__ __forceinline__ ushort_t f2bf(float f) {
    uint32 u = __float_as_uint(f);
    return (ushort_t)((u + 0x7fffu + ((u >> 16) & 1u)) >> 16);
}
__device__ __forceinline__ float bf2f(ushort_t h) {
    return __uint_as_float(((uint32)h) << 16);
}

// ---------------- K1: build_mask || W swizzle (incl hc) || pad/gf clear ------
__global__ __launch_bounds__(512) void prep_kernel(
        const int* __restrict__ ei, int E, int nbB,
        u64* __restrict__ M, u64* __restrict__ MT,
        const float* __restrict__ e1, const float* __restrict__ e2,
        const float* __restrict__ gi, const float* __restrict__ gl,
        const float* __restrict__ go, const float* __restrict__ pj,
        const float* __restrict__ hw1, const float* __restrict__ hw2,
        ushort_t* __restrict__ hi, ushort_t* __restrict__ lo,
        ushort_t* __restrict__ xah, ushort_t* __restrict__ xal,
        ushort_t* __restrict__ xbh, ushort_t* __restrict__ xbl,
        float* __restrict__ gf) {
    int b = blockIdx.x;
    int t = threadIdx.x;
    if (b < nbB) {
        int e = b * 512 + t;
        if (e >= E) return;
        int s = ei[e];
        int d = ei[E + e];
        atomicOr(&M[(size_t)s * WORDS + (d >> 6)], 1ull << (d & 63));
        atomicOr(&MT[(size_t)d * WORDS + (s >> 6)], 1ull << (s & 63));
        return;
    }
    int wb = b - nbB;
    if (wb < 960) {                       // main W: 491520 elems exactly
        int i = wb * 512 + t;
        float v;
        if (i < 131072)      v = (i < 65536) ? e1[i] : e2[i - 65536];
        else if (i < 196608) v = gi[i - 131072];
        else if (i < 393216) v = gl[i - 196608];
        else if (i < 458752) v = go[i - 393216];
        else                 v = pj[i - 458752];
        int base = (i < 458752) ? (i & ~65535) : 458752;
        int r = i - base;
        int col = r >> 8, k = r & 255;
        int ct = col >> 4, fr = col & 15;
        int c = k >> 5, fq = (k >> 3) & 3, j = k & 7;
        int o = base + (ct * 8 + c) * 512 + (fq * 16 + fr) * 8 + j;
        ushort_t h = f2bf(v);
        hi[o] = h;
        lo[o] = f2bf(v - bf2f(h));
        return;
    }
    if (wb < 976) {                       // hc_w1: 64 cols x 128 k
        int i2 = (wb - 960) * 512 + t;    // [0, 8192)
        int col = i2 >> 7, k = i2 & 127;
        float v = hw1[(size_t)col * 128 + k];
        int o = HCW1B + ((col >> 4) * 8 + (k >> 5)) * 512
              + (((k >> 3) & 3) * 16 + (col & 15)) * 8 + (k & 7);
        ushort_t h = f2bf(v);
        hi[o] = h;
        lo[o] = f2bf(v - bf2f(h));
        return;
    }
    if (wb == 976) {                      // hc_w2: 8 cols x 64 k (+ zero cols 8-15)
        int col = t >> 6, k = t & 63;
        float v = hw2[(size_t)col * 64 + k];
        int o = HCW2B + (k >> 5) * 512 + (((k >> 3) & 3) * 16 + col) * 8 + (k & 7);
        ushort_t h = f2bf(v);
        hi[o] = h;
        lo[o] = f2bf(v - bf2f(h));
        int oz = HCW2B + (k >> 5) * 512 + (((k >> 3) & 3) * 16 + 8 + col) * 8 + (k & 7);
        hi[oz] = 0;
        lo[oz] = 0;
        return;
    }
    // pad rows of X ping-pong pairs + gf zero
    #pragma unroll
    for (int k = 0; k < 4; ++k) {
        size_t off = (size_t)NNODES * 256 + (size_t)k * 512 + t;
        xah[off] = 0; xal[off] = 0; xbh[off] = 0; xbl[off] = 0;
    }
    if (t < 128) gf[t] = 0.0f;
}

// ---------------- gather accumulate helpers ----------------
__device__ __forceinline__ void acc_u4(uint4 u, f32x2* a2) {
    const uint32 HM = 0xFFFF0000u;
    f32x2 t0 = {__uint_as_float(u.x << 16), __uint_as_float(u.x & HM)};
    f32x2 t1 = {__uint_as_float(u.y << 16), __uint_as_float(u.y & HM)};
    f32x2 t2 = {__uint_as_float(u.z << 16), __uint_as_float(u.z & HM)};
    f32x2 t3 = {__uint_as_float(u.w << 16), __uint_as_float(u.w & HM)};
    a2[0] += t0; a2[1] += t1; a2[2] += t2; a2[3] += t3;
}

// combine self (hi+lo) + dv*acc over 8 cols, split back into bf16 hi/lo octets
__device__ __forceinline__ void pack_pair(uint4 uh, uint4 ul, const float* a, float dv,
                                          short8_t& oh, short8_t& ol) {
    const uint32 HM = 0xFFFF0000u;
    uint32 hu[4] = {uh.x, uh.y, uh.z, uh.w};
    uint32 lu[4] = {ul.x, ul.y, ul.z, ul.w};
    #pragma unroll
    for (int q = 0; q < 4; ++q) {
        float xlo = __uint_as_float(hu[q] << 16) + __uint_as_float(lu[q] << 16);
        float xhi = __uint_as_float(hu[q] & HM) + __uint_as_float(lu[q] & HM);
        float s0 = xlo + dv * a[2 * q];
        float s1 = xhi + dv * a[2 * q + 1];
        ushort_t p0 = f2bf(s0), p1 = f2bf(s1);
        oh[2 * q]     = (short)p0;
        oh[2 * q + 1] = (short)p1;
        ol[2 * q]     = (short)f2bf(s0 - bf2f(p0));
        ol[2 * q + 1] = (short)f2bf(s1 - bf2f(p1));
    }
}

// ---------------- 16-row band-GEMM (frag-swizzled A in LDS, B from L2) -------
// A-frag LDS: c-blocks of LDB shorts, addr = c*LDB + (fq*16 + r)*8 + j
template<int NTW, int NC>
__device__ __forceinline__ void band_step16(
        const ushort_t* Ah, const ushort_t* Al,
        const ushort_t* __restrict__ Wh, const ushort_t* __restrict__ Wl,
        int w, int lane, f32x4 (&acc)[NTW]) {
    int ct0 = w * NTW;
    short8_t bh[NTW], bl[NTW];
    #pragma unroll
    for (int nt = 0; nt < NTW; ++nt) {
        size_t bo = (size_t)((ct0 + nt) * 8) * 512 + lane * 8;
        bh[nt] = *(const short8_t*)&Wh[bo];
        bl[nt] = *(const short8_t*)&Wl[bo];
    }
    #pragma unroll
    for (int c = 0; c < NC; ++c) {
        short8_t bhn[NTW], bln[NTW];
        if (c < NC - 1) {
            #pragma unroll
            for (int nt = 0; nt < NTW; ++nt) {
                size_t bo = (size_t)((ct0 + nt) * 8 + c + 1) * 512 + lane * 8;
                bhn[nt] = *(const short8_t*)&Wh[bo];
                bln[nt] = *(const short8_t*)&Wl[bo];
            }
        }
        short8_t ah = *(const short8_t*)&Ah[c * LDB + lane * 8];
        short8_t al = *(const short8_t*)&Al[c * LDB + lane * 8];
        #pragma unroll
        for (int nt = 0; nt < NTW; ++nt) {
            f32x4 a = acc[nt];
            a = __builtin_amdgcn_mfma_f32_16x16x32_bf16(ah, bh[nt], a, 0, 0, 0);
            a = __builtin_amdgcn_mfma_f32_16x16x32_bf16(ah, bl[nt], a, 0, 0, 0);
            a = __builtin_amdgcn_mfma_f32_16x16x32_bf16(al, bh[nt], a, 0, 0, 0);
            acc[nt] = a;
        }
        if (c < NC - 1) {
            #pragma unroll
            for (int nt = 0; nt < NTW; ++nt) { bh[nt] = bhn[nt]; bl[nt] = bln[nt]; }
        }
    }
}

template<int NTW>
__device__ __forceinline__ void acc_zero16(f32x4 (&acc)[NTW]) {
    #pragma unroll
    for (int b = 0; b < NTW; ++b) {
        f32x4 z = {0.f, 0.f, 0.f, 0.f};
        acc[b] = z;
    }
}

// bias + optional relu, split to hi/lo, store in FRAG layout for next step
template<int NTW, bool RELU>
__device__ __forceinline__ void acc_to_lds16(
        f32x4 (&acc)[NTW], const float* __restrict__ bias,
        int w, int lane, ushort_t* Ah, ushort_t* Al) {
    int fr = lane & 15, fq = lane >> 4;
    int col0 = w * (16 * NTW);
    #pragma unroll
    for (int nt = 0; nt < NTW; ++nt) {
        int col = col0 + 16 * nt + fr;         // next-step k index
        float bb = bias[col];
        int c = col >> 5, fqn = (col >> 3) & 3, jn = col & 7;
        #pragma unroll
        for (int e = 0; e < 4; ++e) {
            int r = fq * 4 + e;                // 0..15
            float v = acc[nt][e] + bb;
            if (RELU) v = fmaxf(v, 0.0f);
            ushort_t h = f2bf(v);
            int addr = c * LDB + (fqn * 16 + r) * 8 + jn;
            Ah[addr] = h;
            Al[addr] = f2bf(v - bf2f(h));
        }
    }
}

// bias + relu, split hi/lo into ROW-MAJOR [16][RMS] bounce buffers
__device__ __forceinline__ void acc_to_rows(
        f32x4 (&acc)[2], const float* __restrict__ bias,
        int w, int lane, ushort_t* Rh, ushort_t* Rl) {
    int fr = lane & 15, fq = lane >> 4;
    int col0 = w * 32;
    #pragma unroll
    for (int nt = 0; nt < 2; ++nt) {
        int gc = col0 + 16 * nt + fr;
        float bb = bias[gc];
        #pragma unroll
        for (int e = 0; e < 4; ++e) {
            int r = fq * 4 + e;
            float v = fmaxf(acc[nt][e] + bb, 0.0f);
            ushort_t h = f2bf(v);
            Rh[r * RMS + gc] = h;
            Rl[r * RMS + gc] = f2bf(v - bf2f(h));
        }
    }
}

// coalesced flush of row-major bounce buffers to global [N][256] pair
__device__ __forceinline__ void rows_to_global(
        const ushort_t* Rh, const ushort_t* Rl, int row0, int tid,
        ushort_t* __restrict__ Yh, ushort_t* __restrict__ Yl) {
    int r = tid >> 5, kq = tid & 31;
    short8_t vh = *(const short8_t*)&Rh[r * RMS + kq * 8];
    short8_t vl = *(const short8_t*)&Rl[r * RMS + kq * 8];
    size_t off = (size_t)(row0 + r) * 256 + kq * 8;
    *(short8_t*)&Yh[off] = vh;
    *(short8_t*)&Yl[off] = vl;
}

// -------- two-phase col-split gather: phase p covers cols [p*128, p*128+128) --
// Per-phase live X working set = 3.15 MB < 4 MB L2/XCD (vs 6.3 MB monolithic,
// which measured 20% L2 miss / 82 MB fetch per layer). Whole grid co-resident
// (24 waves/CU) so phases stay chip-synchronized.
// Thread = (team h, row r of 16, cg of 16); teams split neighbor 8-groups
// {h, h+2, ...} (round-6-verified: absmax bit-identical). Team 1 parks f32
// partials in PB; team 0 combines (a_h0 + a_h1), packs, writes frag c-blocks.
__device__ __forceinline__ void gather_band2(
        const ushort_t* __restrict__ Xh_, const ushort_t* __restrict__ Xl_,
        const ushort_t* __restrict__ ell, const int* __restrict__ cnt,
        const float* __restrict__ dinv, int row0, int tid,
        ushort_t* Ah, ushort_t* Al, float* PB) {
    int h = tid >> 8;                  // team 0/1
    int t2 = tid & 255;
    int r = t2 >> 4, cg = t2 & 15;
    int row = row0 + r;
    int n = cnt[row];
    int np8 = (n + 7) & ~7;
    const ushort_t* rell = ell + (size_t)row * ELLW;
    float dv = dinv[row];
    #pragma unroll
    for (int p = 0; p < 2; ++p) {
        const ushort_t* xb = Xh_ + p * 128 + cg * 8;
        f32x2 a2[4] = {};
        ushort4 ja = *(const ushort4*)&rell[h * 8];
        ushort4 jb = *(const ushort4*)&rell[h * 8 + 4];
        for (int i = h * 8; i < np8; i += 16) {
            ushort4 jan = *(const ushort4*)&rell[i + 16];
            ushort4 jbn = *(const ushort4*)&rell[i + 20];
            uint4 u0 = *(const uint4*)&xb[(size_t)ja.x * 256];
            uint4 u1 = *(const uint4*)&xb[(size_t)ja.y * 256];
            uint4 u2 = *(const uint4*)&xb[(size_t)ja.z * 256];
            uint4 u3 = *(const uint4*)&xb[(size_t)ja.w * 256];
            uint4 u4 = *(const uint4*)&xb[(size_t)jb.x * 256];
            uint4 u5 = *(const uint4*)&xb[(size_t)jb.y * 256];
            uint4 u6 = *(const uint4*)&xb[(size_t)jb.z * 256];
            uint4 u7 = *(const uint4*)&xb[(size_t)jb.w * 256];
            acc_u4(u0, a2); acc_u4(u1, a2); acc_u4(u2, a2); acc_u4(u3, a2);
            acc_u4(u4, a2); acc_u4(u5, a2); acc_u4(u6, a2); acc_u4(u7, a2);
            ja = jan; jb = jbn;
        }
        if (h) {
            *(float4*)&PB[t2 * PBF] =
                make_float4(a2[0][0], a2[0][1], a2[1][0], a2[1][1]);
            *(float4*)&PB[t2 * PBF + 4] =
                make_float4(a2[2][0], a2[2][1], a2[3][0], a2[3][1]);
        }
        __syncthreads();
        if (!h) {
            float4 p0 = *(const float4*)&PB[t2 * PBF];
            float4 p1 = *(const float4*)&PB[t2 * PBF + 4];
            a2[0][0] += p0.x; a2[0][1] += p0.y;
            a2[1][0] += p0.z; a2[1][1] += p0.w;
            a2[2][0] += p1.x; a2[2][1] += p1.y;
            a2[3][0] += p1.z; a2[3][1] += p1.w;
            const float* a = (const float*)a2;
            size_t so = (size_t)row * 256 + p * 128 + cg * 8;
            uint4 h0 = *(const uint4*)&Xh_[so];
            uint4 l0 = *(const uint4*)&Xl_[so];
            short8_t gh, gl;
            pack_pair(h0, l0, a, dv, gh, gl);
            // frag: k = p*128 + cg*8 + j -> c = p*4 + (cg>>2), fq = cg&3
            int addr = (p * 4 + (cg >> 2)) * LDB + ((cg & 3) * 16 + r) * 8;
            *(short8_t*)&Ah[addr] = gh;
            *(short8_t*)&Al[addr] = gl;
        }
        if (p == 0) __syncthreads();   // PB reused by phase 1
    }
}

// ---------------- K2: fused encoder || ell_fill ----------------
__global__ __launch_bounds__(512) void enc_ell_kernel(
        const float* __restrict__ nf,
        const ushort_t* __restrict__ Wh, const ushort_t* __restrict__ Wl,
        const float* __restrict__ b1, const float* __restrict__ b2,
        const float* __restrict__ b3,
        ushort_t* __restrict__ xh, ushort_t* __restrict__ xl,
        const u64* __restrict__ M, const u64* __restrict__ MT,
        ushort_t* __restrict__ ell, int* __restrict__ cnt, float* __restrict__ dinv) {
    __shared__ __align__(16) ushort_t Ah[16 * RMS];
    __shared__ __align__(16) ushort_t Al[16 * RMS];
    int tid = threadIdx.x;
    int lane = tid & 63;
    if (blockIdx.x >= 768) {
        // ---- ell_fill branch: one wave per row ----
        int row = (blockIdx.x - 768) * 8 + (tid >> 6);
        const u64* rM  = M  + (size_t)row * WORDS;
        const u64* rMT = MT + (size_t)row * WORDS;
        u64 wm[3], wt[3];
        int pm = 0, pt = 0;
        #pragma unroll
        for (int k = 0; k < 3; ++k) {
            wm[k] = rM[lane + 64 * k];  pm += __popcll(wm[k]);
            wt[k] = rMT[lane + 64 * k]; pt += __popcll(wt[k]);
        }
        int inclM = pm, inclT = pt;
        #pragma unroll
        for (int off = 1; off < 64; off <<= 1) {
            int ym = __shfl_up(inclM, off, 64);
            int yt = __shfl_up(inclT, off, 64);
            if (lane >= off) { inclM += ym; inclT += yt; }
        }
        int exclM = inclM - pm;
        int exclT = inclT - pt;
        int totM = __shfl(inclM, 63, 64);
        int totT = __shfl(inclT, 63, 64);
        ushort_t* out = ell + (size_t)row * ELLW;
        int pos = exclM;
        #pragma unroll
        for (int k = 0; k < 3; ++k) {
            u64 bits = wm[k];
            int base = (lane + 64 * k) << 6;
            while (bits) { out[pos++] = (ushort_t)(base + __builtin_ctzll(bits)); bits &= bits - 1; }
        }
        pos = totM + exclT;
        #pragma unroll
        for (int k = 0; k < 3; ++k) {
            u64 bits = wt[k];
            int base = (lane + 64 * k) << 6;
            while (bits) { out[pos++] = (ushort_t)(base + __builtin_ctzll(bits)); bits &= bits - 1; }
        }
        if (lane == 0) {
            int n = totM + totT;
            int np = (n + 7) & ~7;
            for (int p = n; p < np; ++p) out[p] = (ushort_t)ZROW;
            cnt[row] = n;
            dinv[row] = 1.0f / ((float)n + 1e-8f);
        }
        return;
    }
    // ---- encoder branch ----
    int w = __builtin_amdgcn_readfirstlane(tid >> 6);   // 0..7
    int row0 = blockIdx.x * 16;

    // stage nf band (16 rows x 64 float4) with on-the-fly hi/lo split
    #pragma unroll
    for (int i = 0; i < 2; ++i) {
        int s = i * 512 + tid;             // 1024 float4 slots
        int r = s >> 6, k4 = s & 63;
        float4 v = *(const float4*)&nf[(size_t)(row0 + r) * 256 + k4 * 4];
        ushort_t h0 = f2bf(v.x), h1 = f2bf(v.y), h2 = f2bf(v.z), h3 = f2bf(v.w);
        int kq = k4 >> 1, half = (k4 & 1) * 4;
        int c = kq >> 2, fqs = kq & 3;
        int addr = c * LDB + (fqs * 16 + r) * 8 + half;
        *(ushort4*)&Ah[addr] = make_ushort4(h0, h1, h2, h3);
        *(ushort4*)&Al[addr] =
            make_ushort4(f2bf(v.x - bf2f(h0)), f2bf(v.y - bf2f(h1)),
                         f2bf(v.z - bf2f(h2)), f2bf(v.w - bf2f(h3)));
    }
    __syncthreads();

    f32x4 acc[2];
    // enc1 (relu)
    acc_zero16<2>(acc);
    band_step16<2, 8>(Ah, Al, Wh, Wl, w, lane, acc);
    __syncthreads();
    acc_to_lds16<2, true>(acc, b1, w, lane, Ah, Al);
    __syncthreads();
    // enc2 (no relu)
    acc_zero16<2>(acc);
    band_step16<2, 8>(Ah, Al, Wh + 65536, Wl + 65536, w, lane, acc);
    __syncthreads();
    acc_to_lds16<2, false>(acc, b2, w, lane, Ah, Al);
    __syncthreads();
    // gin (relu) -> row-major bounce -> coalesced X0 pair stores
    acc_zero16<2>(acc);
    band_step16<2, 8>(Ah, Al, Wh + 131072, Wl + 131072, w, lane, acc);
    __syncthreads();
    acc_to_rows(acc, b3, w, lane, Ah, Al);
    __syncthreads();
    rows_to_global(Ah, Al, row0, tid, xh, xl);
}

// ---------------- fused GNN layer (layers 1,2): gather -> GEMM -> Y ----------
__global__ __launch_bounds__(512, 4) void fused_layer_kernel(
        const ushort_t* __restrict__ Xh_, const ushort_t* __restrict__ Xl_,
        const ushort_t* __restrict__ ell, const int* __restrict__ cnt,
        const float* __restrict__ dinv,
        const ushort_t* __restrict__ Wh, const ushort_t* __restrict__ Wl,
        const float* __restrict__ bias,
        ushort_t* __restrict__ Yh, ushort_t* __restrict__ Yl) {
    __shared__ __align__(16) ushort_t Ah[16 * RMS];
    __shared__ __align__(16) ushort_t Al[16 * RMS];
    __shared__ __align__(16) float PB[256 * PBF];
    int tid = threadIdx.x;
    int lane = tid & 63;
    int w = __builtin_amdgcn_readfirstlane(tid >> 6);
    int row0 = blockIdx.x * 16;
    gather_band2(Xh_, Xl_, ell, cnt, dinv, row0, tid, Ah, Al, PB);
    __syncthreads();
    f32x4 acc[2];
    acc_zero16<2>(acc);
    band_step16<2, 8>(Ah, Al, Wh, Wl, w, lane, acc);
    __syncthreads();                       // frag reads done -> reuse as bounce
    acc_to_rows(acc, bias, w, lane, Ah, Al);
    __syncthreads();
    rows_to_global(Ah, Al, row0, tid, Yh, Yl);
}

// ------- fused last layer + output: gather -> gl3 -> gout -> proj -> hc -------
__global__ __launch_bounds__(512, 4) void fused_layer_out_kernel(
        const ushort_t* __restrict__ Xh_, const ushort_t* __restrict__ Xl_,
        const ushort_t* __restrict__ ell, const int* __restrict__ cnt,
        const float* __restrict__ dinv,
        const ushort_t* __restrict__ Wh, const ushort_t* __restrict__ Wl,
        const float* __restrict__ gl_b2,
        const float* __restrict__ gout_b, const float* __restrict__ proj_b,
        const float* __restrict__ hc_b1, const float* __restrict__ hc_b2,
        float* __restrict__ ne, float* __restrict__ logits, float* __restrict__ gf) {
    __shared__ __align__(16) ushort_t Ah[16 * RMS];   // frag uses first 8*LDB
    __shared__ __align__(16) ushort_t Al[16 * RMS];
    __shared__ __align__(16) float PB[256 * PBF];
    __shared__ __align__(16) float Pf[16 * 132];      // exact f32 proj (ne + mean)
    int tid = threadIdx.x;
    int lane = tid & 63;
    int w = __builtin_amdgcn_readfirstlane(tid >> 6);
    int row0 = blockIdx.x * 16;
    int fr = lane & 15, fq = lane >> 4;

    // layer-3 gather (into frag LDS) + GEMM; result stays on-chip
    gather_band2(Xh_, Xl_, ell, cnt, dinv, row0, tid, Ah, Al, PB);
    __syncthreads();
    f32x4 acc[2];
    acc_zero16<2>(acc);
    band_step16<2, 8>(Ah, Al, Wh + 327680, Wl + 327680, w, lane, acc);
    __syncthreads();
    acc_to_lds16<2, true>(acc, gl_b2, w, lane, Ah, Al);
    __syncthreads();

    // gout (no relu) -> frag LDS pair
    acc_zero16<2>(acc);
    band_step16<2, 8>(Ah, Al, Wh + 393216, Wl + 393216, w, lane, acc);
    __syncthreads();
    acc_to_lds16<2, false>(acc, gout_b, w, lane, Ah, Al);
    __syncthreads();

    // proj (relu), 128 cols: 8 waves x 16 cols
    f32x4 acc2[1];
    acc_zero16<1>(acc2);
    band_step16<1, 8>(Ah, Al, Wh + 458752, Wl + 458752, w, lane, acc2);
    __syncthreads();   // all frag reads done

    // proj out -> Pf (exact f32) + frag c0-3 (bf16 pair, hc1 A-operand)
    {
        int gc = w * 16 + fr;
        float bb = proj_b[gc];
        int c = gc >> 5, fqn = (gc >> 3) & 3, jn = gc & 7;
        #pragma unroll
        for (int e = 0; e < 4; ++e) {
            int r = fq * 4 + e;
            float v = fmaxf(acc2[0][e] + bb, 0.0f);
            Pf[r * 132 + gc] = v;
            ushort_t h = f2bf(v);
            int addr = c * LDB + (fqn * 16 + r) * 8 + jn;
            Ah[addr] = h;
            Al[addr] = f2bf(v - bf2f(h));
        }
    }
    __syncthreads();

    // phase: ne bounce (all) || gf mean (tids 128-255) || hc1 MFMA (waves 0-3)
    {
        int r = tid >> 5, k4 = tid & 31;
        float4 x = *(const float4*)&Pf[r * 132 + k4 * 4];
        *(float4*)&ne[(size_t)(row0 + r) * 128 + k4 * 4] = x;
    }
    if (tid >= 128 && tid < 256) {
        int col = tid - 128;
        float s = 0.0f;
        #pragma unroll 4
        for (int r = 0; r < 16; ++r) s += Pf[r * 132 + col];
        atomicAdd(&gf[col], s * (1.0f / (float)NNODES));
    }
    if (w < 4) {
        // hc1 (relu): K=128 (c0-3), 64 cols = 4 waves x 16; out -> frag c4,5
        f32x4 acc3[1];
        acc_zero16<1>(acc3);
        band_step16<1, 4>(Ah, Al, Wh + HCW1B, Wl + HCW1B, w, lane, acc3);
        int col64 = w * 16 + fr;
        float bb = hc_b1[col64];
        int c = 4 + (col64 >> 5), fqn = (col64 >> 3) & 3, jn = col64 & 7;
        #pragma unroll
        for (int e = 0; e < 4; ++e) {
            int r = fq * 4 + e;
            float v = fmaxf(acc3[0][e] + bb, 0.0f);
            ushort_t h = f2bf(v);
            int addr = c * LDB + (fqn * 16 + r) * 8 + jn;
            Ah[addr] = h;
            Al[addr] = f2bf(v - bf2f(h));
        }
    }
    __syncthreads();

    // hc2: K=64 from frag c4,5; one wave; cols 0-7 valid (8-15 zero-padded W)
    if (w == 0) {
        f32x4 acc4[1];
        acc_zero16<1>(acc4);
        band_step16<1, 2>(Ah + 4 * LDB, Al + 4 * LDB,
                          Wh + HCW2B, Wl + HCW2B, 0, lane, acc4);
        if (fr < 8) {
            float bb = hc_b2[fr];
            #pragma unroll
            for (int e = 0; e < 4; ++e) {
                int r = fq * 4 + e;
                logits[(size_t)(row0 + r) * 8 + fr] = acc4[0][e] + bb;
            }
        }
    }
}

extern "C" void kernel_launch(void* const* d_in, const int* in_sizes, int n_in,
                              void* d_out, int out_size, void* d_ws, size_t ws_size,
                              hipStream_t stream) {
    const int N = NNODES;
    const float* nf     = (const float*)d_in[0];
    const int*   ei     = (const int*)d_in[1];
    const float* enc_w1 = (const float*)d_in[2];
    const float* enc_b1 = (const float*)d_in[3];
    const float* enc_w2 = (const float*)d_in[4];
    const float* enc_b2 = (const float*)d_in[5];
    const float* gin_w  = (const float*)d_in[6];
    const float* gin_b  = (const float*)d_in[7];
    const float* gl_w   = (const float*)d_in[8];
    const float* gl_b   = (const float*)d_in[9];
    const float* gout_w = (const float*)d_in[10];
    const float* gout_b = (const float*)d_in[11];
    const float* proj_w = (const float*)d_in[12];
    const float* proj_b = (const float*)d_in[13];
    const float* hc_w1  = (const float*)d_in[14];
    const float* hc_b1  = (const float*)d_in[15];
    const float* hc_w2  = (const float*)d_in[16];
    const float* hc_b2  = (const float*)d_in[17];
    const int E = in_sizes[1] >> 1;

    // workspace carve (bytes) -- no aliasing (ws is 256 MiB):
    char* ws = (char*)d_ws;
    u64* M  = (u64*)ws;                                         // 18,874,368
    u64* MT = (u64*)(ws + 18874368);                            // 18,874,368
    ushort_t* XAh = (ushort_t*)(ws + 37748736);                 //  6,295,552
    ushort_t* XAl = (ushort_t*)(ws + 44044288);                 //  6,295,552
    ushort_t* XBh = (ushort_t*)(ws + 50339840);                 //  6,295,552
    ushort_t* XBl = (ushort_t*)(ws + 56635392);                 //  6,295,552
    ushort_t* ell = (ushort_t*)(ws + 62930944);                 //  6,291,456
    int*      cntb = (int*)(ws + 69222400);                     //     49,152
    float*    dinv = (float*)(ws + 69271552);                   //     49,152
    ushort_t* Whi  = (ushort_t*)(ws + 69320704);                //  1,024,000
    ushort_t* Wlo  = (ushort_t*)(ws + 70344704);                //  1,024,000

    float* ne     = (float*)d_out;                        // [N,128]
    float* logits = ne + (size_t)N * 128;                 // [N,8]
    float* gf     = logits + (size_t)N * 8;               // [128]

    hipMemsetAsync(M, 0, 2 * (size_t)N * WORDS * sizeof(u64), stream);

    // K1: build_mask || W swizzle (incl hc_w1/hc_w2) || pad+gf clear
    const int nbB = (E + 511) / 512;       // 768 for E=393216
    prep_kernel<<<nbB + 978, 512, 0, stream>>>(
        ei, E, nbB, M, MT,
        enc_w1, enc_w2, gin_w, gl_w, gout_w, proj_w, hc_w1, hc_w2,
        Whi, Wlo, XAh, XAl, XBh, XBl, gf);

    // K2: fused encoder (768 blocks) || ell_fill (1536 blocks, 8 rows each)
    enc_ell_kernel<<<768 + N / 8, 512, 0, stream>>>(
        nf, Whi, Wlo, enc_b1, enc_b2, gin_b, XAh, XAl,
        M, MT, ell, cntb, dinv);

    const int GB = N / 16;   // 768 band blocks
    // layers 1,2 ping-pong XA<->XB; layer 3 fused with the output chain
    fused_layer_kernel<<<GB, 512, 0, stream>>>(XAh, XAl, ell, cntb, dinv,
                                               Whi + 196608, Wlo + 196608,
                                               gl_b, XBh, XBl);
    fused_layer_kernel<<<GB, 512, 0, stream>>>(XBh, XBl, ell, cntb, dinv,
                                               Whi + 262144, Wlo + 262144,
                                               gl_b + 256, XAh, XAl);
    fused_layer_out_kernel<<<GB, 512, 0, stream>>>(
        XAh, XAl, ell, cntb, dinv, Whi, Wlo, gl_b + 512,
        gout_b, proj_b, hc_b1, hc_b2,
        ne, logits, gf);
}

// Round 9
// 290.541 us; speedup vs baseline: 1.5132x; 1.0345x over previous
//
#include <hip/hip_runtime.h>

typedef unsigned long long u64;
typedef unsigned short ushort_t;
typedef unsigned int uint32;

#define NNODES 12288
#define WORDS 192    // 12288 / 64 bits per row
#define ELLW 256     // max neighbors per row (avg ~64)
#define ZROW NNODES  // zeroed pad row index
#define LDB 520      // LDS A-frag c-block stride in shorts (bank-rotates 4 words/block)
#define RMS 264      // row-major bounce stride in shorts ([16][264])
#define HCW1B 491520 // frag base of hc_w1 (64x128) in W buffer
#define HCW2B 507904 // frag base of hc_w2 (8x64, cols 8-15 zeroed)

typedef __attribute__((ext_vector_type(8))) short short8_t;   // 8 bf16 (4 VGPRs)
typedef __attribute__((ext_vector_type(4))) float f32x4;      // MFMA C/D frag
typedef __attribute__((ext_vector_type(2))) float f32x2;      // packed-add pair

// ---- bf16 split helpers (RNE) ----
__device__ __forceinline__ ushort_t f2bf(float f) {
    uint32 u = __float_as_uint(f);
    return (ushort_t)((u + 0x7fffu + ((u >> 16) & 1u)) >> 16);
}
__device__ __forceinline__ float bf2f(ushort_t h) {
    return __uint_as_float(((uint32)h) << 16);
}

// ---------------- K1: build_mask || W swizzle (incl hc) || pad/gf clear ------
__global__ __launch_bounds__(512) void prep_kernel(
        const int* __restrict__ ei, int E, int nbB,
        u64* __restrict__ M, u64* __restrict__ MT,
        const float* __restrict__ e1, const float* __restrict__ e2,
        const float* __restrict__ gi, const float* __restrict__ gl,
        const float* __restrict__ go, const float* __restrict__ pj,
        const float* __restrict__ hw1, const float* __restrict__ hw2,
        ushort_t* __restrict__ hi, ushort_t* __restrict__ lo,
        ushort_t* __restrict__ xah, ushort_t* __restrict__ xal,
        ushort_t* __restrict__ xbh, ushort_t* __restrict__ xbl,
        float* __restrict__ gf) {
    int b = blockIdx.x;
    int t = threadIdx.x;
    if (b < nbB) {
        int e = b * 512 + t;
        if (e >= E) return;
        int s = ei[e];
        int d = ei[E + e];
        atomicOr(&M[(size_t)s * WORDS + (d >> 6)], 1ull << (d & 63));
        atomicOr(&MT[(size_t)d * WORDS + (s >> 6)], 1ull << (s & 63));
        return;
    }
    int wb = b - nbB;
    if (wb < 960) {                       // main W: 491520 elems exactly
        int i = wb * 512 + t;
        float v;
        if (i < 131072)      v = (i < 65536) ? e1[i] : e2[i - 65536];
        else if (i < 196608) v = gi[i - 131072];
        else if (i < 393216) v = gl[i - 196608];
        else if (i < 458752) v = go[i - 393216];
        else                 v = pj[i - 458752];
        int base = (i < 458752) ? (i & ~65535) : 458752;
        int r = i - base;
        int col = r >> 8, k = r & 255;
        int ct = col >> 4, fr = col & 15;
        int c = k >> 5, fq = (k >> 3) & 3, j = k & 7;
        int o = base + (ct * 8 + c) * 512 + (fq * 16 + fr) * 8 + j;
        ushort_t h = f2bf(v);
        hi[o] = h;
        lo[o] = f2bf(v - bf2f(h));
        return;
    }
    if (wb < 976) {                       // hc_w1: 64 cols x 128 k
        int i2 = (wb - 960) * 512 + t;    // [0, 8192)
        int col = i2 >> 7, k = i2 & 127;
        float v = hw1[(size_t)col * 128 + k];
        int o = HCW1B + ((col >> 4) * 8 + (k >> 5)) * 512
              + (((k >> 3) & 3) * 16 + (col & 15)) * 8 + (k & 7);
        ushort_t h = f2bf(v);
        hi[o] = h;
        lo[o] = f2bf(v - bf2f(h));
        return;
    }
    if (wb == 976) {                      // hc_w2: 8 cols x 64 k (+ zero cols 8-15)
        int col = t >> 6, k = t & 63;
        float v = hw2[(size_t)col * 64 + k];
        int o = HCW2B + (k >> 5) * 512 + (((k >> 3) & 3) * 16 + col) * 8 + (k & 7);
        ushort_t h = f2bf(v);
        hi[o] = h;
        lo[o] = f2bf(v - bf2f(h));
        int oz = HCW2B + (k >> 5) * 512 + (((k >> 3) & 3) * 16 + 8 + col) * 8 + (k & 7);
        hi[oz] = 0;
        lo[oz] = 0;
        return;
    }
    // pad rows of X ping-pong pairs + gf zero
    #pragma unroll
    for (int k = 0; k < 4; ++k) {
        size_t off = (size_t)NNODES * 256 + (size_t)k * 512 + t;
        xah[off] = 0; xal[off] = 0; xbh[off] = 0; xbl[off] = 0;
    }
    if (t < 128) gf[t] = 0.0f;
}

// ---------------- gather accumulate helpers ----------------
__device__ __forceinline__ void acc_u4(uint4 u, f32x2* a2) {
    const uint32 HM = 0xFFFF0000u;
    f32x2 t0 = {__uint_as_float(u.x << 16), __uint_as_float(u.x & HM)};
    f32x2 t1 = {__uint_as_float(u.y << 16), __uint_as_float(u.y & HM)};
    f32x2 t2 = {__uint_as_float(u.z << 16), __uint_as_float(u.z & HM)};
    f32x2 t3 = {__uint_as_float(u.w << 16), __uint_as_float(u.w & HM)};
    a2[0] += t0; a2[1] += t1; a2[2] += t2; a2[3] += t3;
}

// combine self (hi+lo) + dv*acc over 8 cols, split back into bf16 hi/lo octets
__device__ __forceinline__ void pack_pair(uint4 uh, uint4 ul, const float* a, float dv,
                                          short8_t& oh, short8_t& ol) {
    const uint32 HM = 0xFFFF0000u;
    uint32 hu[4] = {uh.x, uh.y, uh.z, uh.w};
    uint32 lu[4] = {ul.x, ul.y, ul.z, ul.w};
    #pragma unroll
    for (int q = 0; q < 4; ++q) {
        float xlo = __uint_as_float(hu[q] << 16) + __uint_as_float(lu[q] << 16);
        float xhi = __uint_as_float(hu[q] & HM) + __uint_as_float(lu[q] & HM);
        float s0 = xlo + dv * a[2 * q];
        float s1 = xhi + dv * a[2 * q + 1];
        ushort_t p0 = f2bf(s0), p1 = f2bf(s1);
        oh[2 * q]     = (short)p0;
        oh[2 * q + 1] = (short)p1;
        ol[2 * q]     = (short)f2bf(s0 - bf2f(p0));
        ol[2 * q + 1] = (short)f2bf(s1 - bf2f(p1));
    }
}

// ---------------- 16-row band-GEMM (frag-swizzled A in LDS, B from L2) -------
// A-frag LDS: c-blocks of LDB shorts, addr = c*LDB + (fq*16 + r)*8 + j
// NC = number of K-32 c-blocks (8 for K=256, 4 for K=128, 2 for K=64)
template<int NTW, int NC>
__device__ __forceinline__ void band_step16(
        const ushort_t* Ah, const ushort_t* Al,
        const ushort_t* __restrict__ Wh, const ushort_t* __restrict__ Wl,
        int w, int lane, f32x4 (&acc)[NTW]) {
    int ct0 = w * NTW;
    short8_t bh[NTW], bl[NTW];
    #pragma unroll
    for (int nt = 0; nt < NTW; ++nt) {
        size_t bo = (size_t)((ct0 + nt) * 8) * 512 + lane * 8;
        bh[nt] = *(const short8_t*)&Wh[bo];
        bl[nt] = *(const short8_t*)&Wl[bo];
    }
    #pragma unroll
    for (int c = 0; c < NC; ++c) {
        short8_t bhn[NTW], bln[NTW];
        if (c < NC - 1) {
            #pragma unroll
            for (int nt = 0; nt < NTW; ++nt) {
                size_t bo = (size_t)((ct0 + nt) * 8 + c + 1) * 512 + lane * 8;
                bhn[nt] = *(const short8_t*)&Wh[bo];
                bln[nt] = *(const short8_t*)&Wl[bo];
            }
        }
        short8_t ah = *(const short8_t*)&Ah[c * LDB + lane * 8];
        short8_t al = *(const short8_t*)&Al[c * LDB + lane * 8];
        #pragma unroll
        for (int nt = 0; nt < NTW; ++nt) {
            f32x4 a = acc[nt];
            a = __builtin_amdgcn_mfma_f32_16x16x32_bf16(ah, bh[nt], a, 0, 0, 0);
            a = __builtin_amdgcn_mfma_f32_16x16x32_bf16(ah, bl[nt], a, 0, 0, 0);
            a = __builtin_amdgcn_mfma_f32_16x16x32_bf16(al, bh[nt], a, 0, 0, 0);
            acc[nt] = a;
        }
        if (c < NC - 1) {
            #pragma unroll
            for (int nt = 0; nt < NTW; ++nt) { bh[nt] = bhn[nt]; bl[nt] = bln[nt]; }
        }
    }
}

template<int NTW>
__device__ __forceinline__ void acc_zero16(f32x4 (&acc)[NTW]) {
    #pragma unroll
    for (int b = 0; b < NTW; ++b) {
        f32x4 z = {0.f, 0.f, 0.f, 0.f};
        acc[b] = z;
    }
}

// bias + optional relu, split to hi/lo, store in FRAG layout for next step
template<int NTW, bool RELU>
__device__ __forceinline__ void acc_to_lds16(
        f32x4 (&acc)[NTW], const float* __restrict__ bias,
        int w, int lane, ushort_t* Ah, ushort_t* Al) {
    int fr = lane & 15, fq = lane >> 4;
    int col0 = w * (16 * NTW);
    #pragma unroll
    for (int nt = 0; nt < NTW; ++nt) {
        int col = col0 + 16 * nt + fr;         // next-step k index
        float bb = bias[col];
        int c = col >> 5, fqn = (col >> 3) & 3, jn = col & 7;
        #pragma unroll
        for (int e = 0; e < 4; ++e) {
            int r = fq * 4 + e;                // 0..15
            float v = acc[nt][e] + bb;
            if (RELU) v = fmaxf(v, 0.0f);
            ushort_t h = f2bf(v);
            int addr = c * LDB + (fqn * 16 + r) * 8 + jn;
            Ah[addr] = h;
            Al[addr] = f2bf(v - bf2f(h));
        }
    }
}

// bias + relu, split hi/lo into ROW-MAJOR [16][RMS] bounce buffers
__device__ __forceinline__ void acc_to_rows(
        f32x4 (&acc)[2], const float* __restrict__ bias,
        int w, int lane, ushort_t* Rh, ushort_t* Rl) {
    int fr = lane & 15, fq = lane >> 4;
    int col0 = w * 32;
    #pragma unroll
    for (int nt = 0; nt < 2; ++nt) {
        int gc = col0 + 16 * nt + fr;
        float bb = bias[gc];
        #pragma unroll
        for (int e = 0; e < 4; ++e) {
            int r = fq * 4 + e;
            float v = fmaxf(acc[nt][e] + bb, 0.0f);
            ushort_t h = f2bf(v);
            Rh[r * RMS + gc] = h;
            Rl[r * RMS + gc] = f2bf(v - bf2f(h));
        }
    }
}

// coalesced flush of row-major bounce buffers to global [N][256] pair
__device__ __forceinline__ void rows_to_global(
        const ushort_t* Rh, const ushort_t* Rl, int row0, int tid,
        ushort_t* __restrict__ Yh, ushort_t* __restrict__ Yl) {
    int r = tid >> 5, kq = tid & 31;
    short8_t vh = *(const short8_t*)&Rh[r * RMS + kq * 8];
    short8_t vl = *(const short8_t*)&Rl[r * RMS + kq * 8];
    size_t off = (size_t)(row0 + r) * 256 + kq * 8;
    *(short8_t*)&Yh[off] = vh;
    *(short8_t*)&Yl[off] = vl;
}

// ---------------- gather one 16-row band into FRAG LDS ----------------
__device__ __forceinline__ void gather_band(
        const ushort_t* __restrict__ Xh_, const ushort_t* __restrict__ Xl_,
        const ushort_t* __restrict__ ell, const int* __restrict__ cnt,
        const float* __restrict__ dinv, int row0, int tid,
        ushort_t* Ah, ushort_t* Al) {
    int r = tid >> 5, cg = tid & 31;
    int row = row0 + r;
    int n = cnt[row];
    int np8 = (n + 7) & ~7;
    const ushort_t* rell = ell + (size_t)row * ELLW;
    const ushort_t* xb = Xh_ + cg * 8;
    f32x2 a2[4] = {};
    ushort4 ja = *(const ushort4*)&rell[0];
    ushort4 jb = *(const ushort4*)&rell[4];
    for (int i = 0; i < np8; i += 8) {
        ushort4 jan = *(const ushort4*)&rell[i + 8];
        ushort4 jbn = *(const ushort4*)&rell[i + 12];
        uint4 u0 = *(const uint4*)&xb[(size_t)ja.x * 256];
        uint4 u1 = *(const uint4*)&xb[(size_t)ja.y * 256];
        uint4 u2 = *(const uint4*)&xb[(size_t)ja.z * 256];
        uint4 u3 = *(const uint4*)&xb[(size_t)ja.w * 256];
        uint4 u4 = *(const uint4*)&xb[(size_t)jb.x * 256];
        uint4 u5 = *(const uint4*)&xb[(size_t)jb.y * 256];
        uint4 u6 = *(const uint4*)&xb[(size_t)jb.z * 256];
        uint4 u7 = *(const uint4*)&xb[(size_t)jb.w * 256];
        acc_u4(u0, a2); acc_u4(u1, a2); acc_u4(u2, a2); acc_u4(u3, a2);
        acc_u4(u4, a2); acc_u4(u5, a2); acc_u4(u6, a2); acc_u4(u7, a2);
        ja = jan; jb = jbn;
    }
    const float* a = (const float*)a2;
    float dv = dinv[row];
    size_t so = (size_t)row * 256 + cg * 8;
    uint4 h0 = *(const uint4*)&Xh_[so];
    uint4 l0 = *(const uint4*)&Xl_[so];
    short8_t gh, gl;
    pack_pair(h0, l0, a, dv, gh, gl);
    int addr = (cg >> 2) * LDB + ((cg & 3) * 16 + r) * 8;
    *(short8_t*)&Ah[addr] = gh;
    *(short8_t*)&Al[addr] = gl;
}

// ---------------- K2: fused encoder || ell_fill ----------------
__global__ __launch_bounds__(512) void enc_ell_kernel(
        const float* __restrict__ nf,
        const ushort_t* __restrict__ Wh, const ushort_t* __restrict__ Wl,
        const float* __restrict__ b1, const float* __restrict__ b2,
        const float* __restrict__ b3,
        ushort_t* __restrict__ xh, ushort_t* __restrict__ xl,
        const u64* __restrict__ M, const u64* __restrict__ MT,
        ushort_t* __restrict__ ell, int* __restrict__ cnt, float* __restrict__ dinv) {
    __shared__ __align__(16) ushort_t Ah[16 * RMS];
    __shared__ __align__(16) ushort_t Al[16 * RMS];
    int tid = threadIdx.x;
    int lane = tid & 63;
    if (blockIdx.x >= 768) {
        // ---- ell_fill branch: one wave per row ----
        int row = (blockIdx.x - 768) * 8 + (tid >> 6);
        const u64* rM  = M  + (size_t)row * WORDS;
        const u64* rMT = MT + (size_t)row * WORDS;
        u64 wm[3], wt[3];
        int pm = 0, pt = 0;
        #pragma unroll
        for (int k = 0; k < 3; ++k) {
            wm[k] = rM[lane + 64 * k];  pm += __popcll(wm[k]);
            wt[k] = rMT[lane + 64 * k]; pt += __popcll(wt[k]);
        }
        int inclM = pm, inclT = pt;
        #pragma unroll
        for (int off = 1; off < 64; off <<= 1) {
            int ym = __shfl_up(inclM, off, 64);
            int yt = __shfl_up(inclT, off, 64);
            if (lane >= off) { inclM += ym; inclT += yt; }
        }
        int exclM = inclM - pm;
        int exclT = inclT - pt;
        int totM = __shfl(inclM, 63, 64);
        int totT = __shfl(inclT, 63, 64);
        ushort_t* out = ell + (size_t)row * ELLW;
        int pos = exclM;
        #pragma unroll
        for (int k = 0; k < 3; ++k) {
            u64 bits = wm[k];
            int base = (lane + 64 * k) << 6;
            while (bits) { out[pos++] = (ushort_t)(base + __builtin_ctzll(bits)); bits &= bits - 1; }
        }
        pos = totM + exclT;
        #pragma unroll
        for (int k = 0; k < 3; ++k) {
            u64 bits = wt[k];
            int base = (lane + 64 * k) << 6;
            while (bits) { out[pos++] = (ushort_t)(base + __builtin_ctzll(bits)); bits &= bits - 1; }
        }
        if (lane == 0) {
            int n = totM + totT;
            int np = (n + 7) & ~7;
            for (int p = n; p < np; ++p) out[p] = (ushort_t)ZROW;
            cnt[row] = n;
            dinv[row] = 1.0f / ((float)n + 1e-8f);
        }
        return;
    }
    // ---- encoder branch ----
    int w = __builtin_amdgcn_readfirstlane(tid >> 6);   // 0..7
    int row0 = blockIdx.x * 16;

    // stage nf band (16 rows x 64 float4) with on-the-fly hi/lo split
    #pragma unroll
    for (int i = 0; i < 2; ++i) {
        int s = i * 512 + tid;             // 1024 float4 slots
        int r = s >> 6, k4 = s & 63;
        float4 v = *(const float4*)&nf[(size_t)(row0 + r) * 256 + k4 * 4];
        ushort_t h0 = f2bf(v.x), h1 = f2bf(v.y), h2 = f2bf(v.z), h3 = f2bf(v.w);
        int kq = k4 >> 1, half = (k4 & 1) * 4;
        int c = kq >> 2, fqs = kq & 3;
        int addr = c * LDB + (fqs * 16 + r) * 8 + half;
        *(ushort4*)&Ah[addr] = make_ushort4(h0, h1, h2, h3);
        *(ushort4*)&Al[addr] =
            make_ushort4(f2bf(v.x - bf2f(h0)), f2bf(v.y - bf2f(h1)),
                         f2bf(v.z - bf2f(h2)), f2bf(v.w - bf2f(h3)));
    }
    __syncthreads();

    f32x4 acc[2];
    // enc1 (relu)
    acc_zero16<2>(acc);
    band_step16<2, 8>(Ah, Al, Wh, Wl, w, lane, acc);
    __syncthreads();
    acc_to_lds16<2, true>(acc, b1, w, lane, Ah, Al);
    __syncthreads();
    // enc2 (no relu)
    acc_zero16<2>(acc);
    band_step16<2, 8>(Ah, Al, Wh + 65536, Wl + 65536, w, lane, acc);
    __syncthreads();
    acc_to_lds16<2, false>(acc, b2, w, lane, Ah, Al);
    __syncthreads();
    // gin (relu) -> row-major bounce -> coalesced X0 pair stores
    acc_zero16<2>(acc);
    band_step16<2, 8>(Ah, Al, Wh + 131072, Wl + 131072, w, lane, acc);
    __syncthreads();
    acc_to_rows(acc, b3, w, lane, Ah, Al);
    __syncthreads();
    rows_to_global(Ah, Al, row0, tid, xh, xl);
}

// ---------------- fused GNN layer (layers 1,2): gather -> GEMM -> Y ----------
__global__ __launch_bounds__(512, 4) void fused_layer_kernel(
        const ushort_t* __restrict__ Xh_, const ushort_t* __restrict__ Xl_,
        const ushort_t* __restrict__ ell, const int* __restrict__ cnt,
        const float* __restrict__ dinv,
        const ushort_t* __restrict__ Wh, const ushort_t* __restrict__ Wl,
        const float* __restrict__ bias,
        ushort_t* __restrict__ Yh, ushort_t* __restrict__ Yl) {
    __shared__ __align__(16) ushort_t Ah[16 * RMS];
    __shared__ __align__(16) ushort_t Al[16 * RMS];
    int tid = threadIdx.x;
    int lane = tid & 63;
    int w = __builtin_amdgcn_readfirstlane(tid >> 6);
    int row0 = blockIdx.x * 16;
    gather_band(Xh_, Xl_, ell, cnt, dinv, row0, tid, Ah, Al);
    __syncthreads();
    f32x4 acc[2];
    acc_zero16<2>(acc);
    band_step16<2, 8>(Ah, Al, Wh, Wl, w, lane, acc);
    __syncthreads();                       // frag reads done -> reuse as bounce
    acc_to_rows(acc, bias, w, lane, Ah, Al);
    __syncthreads();
    rows_to_global(Ah, Al, row0, tid, Yh, Yl);
}

// ------- fused last layer + output: gather -> gl3 -> gout -> proj -> hc -------
__global__ __launch_bounds__(512, 4) void fused_layer_out_kernel(
        const ushort_t* __restrict__ Xh_, const ushort_t* __restrict__ Xl_,
        const ushort_t* __restrict__ ell, const int* __restrict__ cnt,
        const float* __restrict__ dinv,
        const ushort_t* __restrict__ Wh, const ushort_t* __restrict__ Wl,
        const float* __restrict__ gl_b2,
        const float* __restrict__ gout_b, const float* __restrict__ proj_b,
        const float* __restrict__ hc_b1, const float* __restrict__ hc_b2,
        float* __restrict__ ne, float* __restrict__ logits, float* __restrict__ gf) {
    __shared__ __align__(16) ushort_t Ah[16 * RMS];   // frag uses first 8*LDB
    __shared__ __align__(16) ushort_t Al[16 * RMS];
    __shared__ __align__(16) float Pf[16 * 132];      // exact f32 proj (ne + mean)
    int tid = threadIdx.x;
    int lane = tid & 63;
    int w = __builtin_amdgcn_readfirstlane(tid >> 6);
    int row0 = blockIdx.x * 16;
    int fr = lane & 15, fq = lane >> 4;

    // layer-3 gather (into frag LDS) + GEMM; result stays on-chip
    gather_band(Xh_, Xl_, ell, cnt, dinv, row0, tid, Ah, Al);
    __syncthreads();
    f32x4 acc[2];
    acc_zero16<2>(acc);
    band_step16<2, 8>(Ah, Al, Wh + 327680, Wl + 327680, w, lane, acc);
    __syncthreads();
    acc_to_lds16<2, true>(acc, gl_b2, w, lane, Ah, Al);
    __syncthreads();

    // gout (no relu) -> frag LDS pair
    acc_zero16<2>(acc);
    band_step16<2, 8>(Ah, Al, Wh + 393216, Wl + 393216, w, lane, acc);
    __syncthreads();
    acc_to_lds16<2, false>(acc, gout_b, w, lane, Ah, Al);
    __syncthreads();

    // proj (relu), 128 cols: 8 waves x 16 cols
    f32x4 acc2[1];
    acc_zero16<1>(acc2);
    band_step16<1, 8>(Ah, Al, Wh + 458752, Wl + 458752, w, lane, acc2);
    __syncthreads();   // all frag reads done

    // proj out -> Pf (exact f32) + frag c0-3 (bf16 pair, hc1 A-operand)
    {
        int gc = w * 16 + fr;
        float bb = proj_b[gc];
        int c = gc >> 5, fqn = (gc >> 3) & 3, jn = gc & 7;
        #pragma unroll
        for (int e = 0; e < 4; ++e) {
            int r = fq * 4 + e;
            float v = fmaxf(acc2[0][e] + bb, 0.0f);
            Pf[r * 132 + gc] = v;
            ushort_t h = f2bf(v);
            int addr = c * LDB + (fqn * 16 + r) * 8 + jn;
            Ah[addr] = h;
            Al[addr] = f2bf(v - bf2f(h));
        }
    }
    __syncthreads();

    // phase: ne bounce (all) || gf mean (tids 128-255) || hc1 MFMA (waves 0-3)
    {
        int r = tid >> 5, k4 = tid & 31;
        float4 x = *(const float4*)&Pf[r * 132 + k4 * 4];
        *(float4*)&ne[(size_t)(row0 + r) * 128 + k4 * 4] = x;
    }
    if (tid >= 128 && tid < 256) {
        int col = tid - 128;
        float s = 0.0f;
        #pragma unroll 4
        for (int r = 0; r < 16; ++r) s += Pf[r * 132 + col];
        atomicAdd(&gf[col], s * (1.0f / (float)NNODES));
    }
    if (w < 4) {
        // hc1 (relu): K=128 (c0-3), 64 cols = 4 waves x 16; out -> frag c4,5
        f32x4 acc3[1];
        acc_zero16<1>(acc3);
        band_step16<1, 4>(Ah, Al, Wh + HCW1B, Wl + HCW1B, w, lane, acc3);
        int col64 = w * 16 + fr;
        float bb = hc_b1[col64];
        int c = 4 + (col64 >> 5), fqn = (col64 >> 3) & 3, jn = col64 & 7;
        #pragma unroll
        for (int e = 0; e < 4; ++e) {
            int r = fq * 4 + e;
            float v = fmaxf(acc3[0][e] + bb, 0.0f);
            ushort_t h = f2bf(v);
            int addr = c * LDB + (fqn * 16 + r) * 8 + jn;
            Ah[addr] = h;
            Al[addr] = f2bf(v - bf2f(h));
        }
    }
    __syncthreads();

    // hc2: K=64 from frag c4,5; one wave; cols 0-7 valid (8-15 zero-padded W)
    if (w == 0) {
        f32x4 acc4[1];
        acc_zero16<1>(acc4);
        band_step16<1, 2>(Ah + 4 * LDB, Al + 4 * LDB,
                          Wh + HCW2B, Wl + HCW2B, 0, lane, acc4);
        if (fr < 8) {
            float bb = hc_b2[fr];
            #pragma unroll
            for (int e = 0; e < 4; ++e) {
                int r = fq * 4 + e;
                logits[(size_t)(row0 + r) * 8 + fr] = acc4[0][e] + bb;
            }
        }
    }
}

extern "C" void kernel_launch(void* const* d_in, const int* in_sizes, int n_in,
                              void* d_out, int out_size, void* d_ws, size_t ws_size,
                              hipStream_t stream) {
    const int N = NNODES;
    const float* nf     = (const float*)d_in[0];
    const int*   ei     = (const int*)d_in[1];
    const float* enc_w1 = (const float*)d_in[2];
    const float* enc_b1 = (const float*)d_in[3];
    const float* enc_w2 = (const float*)d_in[4];
    const float* enc_b2 = (const float*)d_in[5];
    const float* gin_w  = (const float*)d_in[6];
    const float* gin_b  = (const float*)d_in[7];
    const float* gl_w   = (const float*)d_in[8];
    const float* gl_b   = (const float*)d_in[9];
    const float* gout_w = (const float*)d_in[10];
    const float* gout_b = (const float*)d_in[11];
    const float* proj_w = (const float*)d_in[12];
    const float* proj_b = (const float*)d_in[13];
    const float* hc_w1  = (const float*)d_in[14];
    const float* hc_b1  = (const float*)d_in[15];
    const float* hc_w2  = (const float*)d_in[16];
    const float* hc_b2  = (const float*)d_in[17];
    const int E = in_sizes[1] >> 1;

    // workspace carve (bytes) -- no aliasing (ws is 256 MiB):
    char* ws = (char*)d_ws;
    u64* M  = (u64*)ws;                                         // 18,874,368
    u64* MT = (u64*)(ws + 18874368);                            // 18,874,368
    ushort_t* XAh = (ushort_t*)(ws + 37748736);                 //  6,295,552
    ushort_t* XAl = (ushort_t*)(ws + 44044288);                 //  6,295,552
    ushort_t* XBh = (ushort_t*)(ws + 50339840);                 //  6,295,552
    ushort_t* XBl = (ushort_t*)(ws + 56635392);                 //  6,295,552
    ushort_t* ell = (ushort_t*)(ws + 62930944);                 //  6,291,456
    int*      cntb = (int*)(ws + 69222400);                     //     49,152
    float*    dinv = (float*)(ws + 69271552);                   //     49,152
    ushort_t* Whi  = (ushort_t*)(ws + 69320704);                //  1,024,000
    ushort_t* Wlo  = (ushort_t*)(ws + 70344704);                //  1,024,000

    float* ne     = (float*)d_out;                        // [N,128]
    float* logits = ne + (size_t)N * 128;                 // [N,8]
    float* gf     = logits + (size_t)N * 8;               // [128]

    hipMemsetAsync(M, 0, 2 * (size_t)N * WORDS * sizeof(u64), stream);

    // K1: build_mask || W swizzle (incl hc_w1/hc_w2) || pad+gf clear
    const int nbB = (E + 511) / 512;       // 768 for E=393216
    prep_kernel<<<nbB + 978, 512, 0, stream>>>(
        ei, E, nbB, M, MT,
        enc_w1, enc_w2, gin_w, gl_w, gout_w, proj_w, hc_w1, hc_w2,
        Whi, Wlo, XAh, XAl, XBh, XBl, gf);

    // K2: fused encoder (768 blocks) || ell_fill (1536 blocks, 8 rows each)
    enc_ell_kernel<<<768 + N / 8, 512, 0, stream>>>(
        nf, Whi, Wlo, enc_b1, enc_b2, gin_b, XAh, XAl,
        M, MT, ell, cntb, dinv);

    const int GB = N / 16;   // 768 band blocks
    // layers 1,2 ping-pong XA<->XB; layer 3 fused with the output chain
    fused_layer_kernel<<<GB, 512, 0, stream>>>(XAh, XAl, ell, cntb, dinv,
                                               Whi + 196608, Wlo + 196608,
                                               gl_b, XBh, XBl);
    fused_layer_kernel<<<GB, 512, 0, stream>>>(XBh, XBl, ell, cntb, dinv,
                                               Whi + 262144, Wlo + 262144,
                                               gl_b + 256, XAh, XAl);
    fused_layer_out_kernel<<<GB, 512, 0, stream>>>(
        XAh, XAl, ell, cntb, dinv, Whi, Wlo, gl_b + 512,
        gout_b, proj_b, hc_b1, hc_b2,
        ne, logits, gf);
}